// Round 11
// baseline (275.697 us; speedup 1.0000x reference)
//
#include <hip/hip_runtime.h>
#include <stdint.h>

// SimpleGCN, f32 in / f32 out. Round 22 = r21 (273.3us best) with F1 given
// 2 blk/CU TLP (the session's most-validated lever: r0/r1/r13/r17 all show
// this 2-barrier structure needs >=2 blocks/CU to cover the vmcnt(0)+barrier
// drain). F1: 128x256/512thr/96KB (grid 256 = 1 blk/CU) -> gemm_f1w64:
// 64(m)x256(n), 256 thr (4 waves of 64x64), BK=128, LDS exactly 80KB ->
// 2 blk/CU, grid (1,128,4) = 512 blocks. P still read ONCE (y splits P rows;
// only Y1T (4MB, L3-resident) is re-read). Same k-chunk order + swz16 scheme
// as refcheck'd gemm_nt128 -> bit-identical (absmax 0.05078125).
//   conv: Fs,Ft,W1 -> f16; W2 -> bf16 (+ MFMA layout probe)
//   G2 : S = Fsf@Ftf^T (f16); P~=exp(S-100)->bf16 [8192][8192] + rowsum partials
//   GY1: Y1T = W1f@Fsf^T (f16) -> bf16 [256][8192]
//   F1 : pp[z] = invl(.)(P~ @ Y1), 64x256 BK=128, split-K=4, FIN folded
//   C1 : x1 = sum4(pp) -> f32 d_out + bf16 x1h
//   GY2: Y2T = W2h@x1h^T (bf16) -> bf16 [128][8192]
//   F2 : pp[z] = invl(.)(P~ @ Y2), 128x128 BK=128, split-K=8, FIN folded
//   C2 : x2 = sum8(pp) -> f32 d_out
// NT GEMMs; BK=64 kernels: 128B LDS rows + swz8; BK=128: 256B rows + swz16.
// Epilogue coords from runtime probe (rmap/cmap).

typedef unsigned short u16;
typedef short bf16x8 __attribute__((ext_vector_type(8)));
typedef _Float16 f16x8 __attribute__((ext_vector_type(8)));
typedef float f32x4 __attribute__((ext_vector_type(4)));

#define EPI_STOREB 0
#define EPI_PARTH  1

__device__ __forceinline__ u16 f2bf(float f) {
  unsigned u = __float_as_uint(f);
  u += 0x7fffu + ((u >> 16) & 1u);
  return (u16)(u >> 16);
}
__device__ __forceinline__ u16 f2h(float f) {
  union { _Float16 h; u16 u; } cv; cv.h = (_Float16)f; return cv.u;
}
__device__ __forceinline__ float h2f(u16 u) {
  union { u16 u; _Float16 h; } cv; cv.u = u; return (float)cv.h;
}
__device__ __forceinline__ int swz8(int r) { return (r ^ (r >> 3)) & 7; }
__device__ __forceinline__ int swz16(int r) { return (r ^ (r >> 4)) & 15; }

__device__ __forceinline__ void async16(const void* g, void* lds) {
  __builtin_amdgcn_global_load_lds(
      (const __attribute__((address_space(1))) unsigned int*)g,
      (__attribute__((address_space(3))) unsigned int*)lds, 16, 0, 0);
}

// ---------------------------------------------------------------------------
// conv + layout probe (r14-proven).
// ---------------------------------------------------------------------------
__global__ __launch_bounds__(256) void conv_probe(
    const float* __restrict__ Fs, const float* __restrict__ Ft,
    const float* __restrict__ W1, const float* __restrict__ W2,
    u16* __restrict__ Fsf, u16* __restrict__ Ftf,
    u16* __restrict__ W1f, u16* __restrict__ W2h,
    int* __restrict__ rmap, int* __restrict__ cmap) {
  const int bx = blockIdx.x, tid = threadIdx.x;
  if (bx < 4176) {
    const float* src; u16* dst; size_t i; bool tobf = false;
    if (bx < 2048)      { src = Fs; dst = Fsf; i = ((size_t)bx * 256 + tid) * 8; }
    else if (bx < 4096) { src = Ft; dst = Ftf; i = ((size_t)(bx - 2048) * 256 + tid) * 8; }
    else if (bx < 4160) { src = W1; dst = W1f; i = ((size_t)(bx - 4096) * 256 + tid) * 8; }
    else                { src = W2; dst = W2h; i = ((size_t)(bx - 4160) * 256 + tid) * 8; tobf = true; }
    const float4 a = *(const float4*)(src + i);
    const float4 b = *(const float4*)(src + i + 4);
    bf16x8 o;
    if (tobf) {
      o[0] = (short)f2bf(a.x); o[1] = (short)f2bf(a.y); o[2] = (short)f2bf(a.z); o[3] = (short)f2bf(a.w);
      o[4] = (short)f2bf(b.x); o[5] = (short)f2bf(b.y); o[6] = (short)f2bf(b.z); o[7] = (short)f2bf(b.w);
    } else {
      o[0] = (short)f2h(a.x); o[1] = (short)f2h(a.y); o[2] = (short)f2h(a.z); o[3] = (short)f2h(a.w);
      o[4] = (short)f2h(b.x); o[5] = (short)f2h(b.y); o[6] = (short)f2h(b.z); o[7] = (short)f2h(b.w);
    }
    *(bf16x8*)(dst + i) = o;
    return;
  }
  if (tid >= 64) return;
  const int lane = tid & 63;
  const int t = lane & 15, quad = lane >> 4;
  bf16x8 avt, av1;
  const u16 bt = f2bf((float)t), b1 = 0x3f80;
#pragma unroll
  for (int j = 0; j < 8; ++j) { ((u16*)&avt)[j] = bt; ((u16*)&av1)[j] = b1; }
  f32x4 z = {0.f, 0.f, 0.f, 0.f};
  f32x4 r1 = __builtin_amdgcn_mfma_f32_16x16x32_bf16(avt, av1, z, 0, 0, 0);
  f32x4 r2 = __builtin_amdgcn_mfma_f32_16x16x32_bf16(av1, avt, z, 0, 0, 0);
#pragma unroll
  for (int e = 0; e < 4; ++e) {
    int r = (int)(r1[e] * 0.03125f + 0.5f);
    int c = (int)(r2[e] * 0.03125f + 0.5f);
    if (r < 0 || r > 15) r = quad * 4 + e;
    if (c < 0 || c > 15) c = t;
    rmap[lane * 4 + e] = r;
    cmap[lane * 4 + e] = c;
  }
}

// ---------------------------------------------------------------------------
// G2: f16 NT GEMM, 256x128 tile, 512 threads, BK=64 (r9/r11 proven, ~92us).
// ---------------------------------------------------------------------------
__global__ __launch_bounds__(512) void gemm_pexp_f16_256(
    const u16* __restrict__ A, const u16* __restrict__ B, int K, int N,
    u16* __restrict__ P, float* __restrict__ rsp,
    const int* __restrict__ rmap, const int* __restrict__ cmap) {
  __shared__ __align__(16) u16 lA[256 * 64];
  __shared__ __align__(16) u16 lB[128 * 64];
  __shared__ float lrs[256][2];

  const int tid = threadIdx.x;
  const int wave = tid >> 6, lane = tid & 63;
  const int quad = lane >> 4, t = lane & 15;
  const int bm = blockIdx.y * 256, bn = blockIdx.x * 128;
  const int wm = (wave & 3) * 64, wn = (wave >> 2) * 64;

  f32x4 acc[4][4];
#pragma unroll
  for (int i = 0; i < 4; ++i)
#pragma unroll
    for (int j = 0; j < 4; ++j) acc[i][j] = (f32x4){0.f, 0.f, 0.f, 0.f};

  const int srow = tid >> 3, schk = tid & 7;
  const u16* pA[4]; const u16* pB[2];
#pragma unroll
  for (int j = 0; j < 4; ++j) {
    const int r = j * 64 + srow;
    pA[j] = A + (size_t)(bm + r) * K + (schk ^ swz8(r)) * 8;
  }
#pragma unroll
  for (int j = 0; j < 2; ++j) {
    const int r = j * 64 + srow;
    pB[j] = B + (size_t)(bn + r) * K + (schk ^ swz8(r)) * 8;
  }

  int aoffx[4], boffx[4];
#pragma unroll
  for (int i = 0; i < 4; ++i) {
    const int rm = wm + i * 16 + t;
    aoffx[i] = rm * 128 + (swz8(rm) << 4);
    const int rn = wn + i * 16 + t;
    boffx[i] = rn * 128 + (swz8(rn) << 4);
  }
  const int sq0 = quad << 4, sq1 = (quad << 4) | 64;

  for (int k0 = 0; k0 < K; k0 += 64) {
#pragma unroll
    for (int j = 0; j < 4; ++j) {
      async16(pA[j], (char*)lA + j * 8192 + wave * 1024);
      pA[j] += 64;
    }
#pragma unroll
    for (int j = 0; j < 2; ++j) {
      async16(pB[j], (char*)lB + j * 8192 + wave * 1024);
      pB[j] += 64;
    }
    __syncthreads();
#pragma unroll
    for (int s = 0; s < 2; ++s) {
      const int sq = s ? sq1 : sq0;
      f16x8 av[4], bv[4];
#pragma unroll
      for (int i = 0; i < 4; ++i) {
        av[i] = *(const f16x8*)((const char*)lA + (aoffx[i] ^ sq));
        bv[i] = *(const f16x8*)((const char*)lB + (boffx[i] ^ sq));
      }
#pragma unroll
      for (int mi = 0; mi < 4; ++mi)
#pragma unroll
        for (int ni = 0; ni < 4; ++ni)
          acc[mi][ni] = __builtin_amdgcn_mfma_f32_16x16x32_f16(av[mi], bv[ni], acc[mi][ni], 0, 0, 0);
    }
    __syncthreads();
  }

  int rl[4], cl[4];
#pragma unroll
  for (int e = 0; e < 4; ++e) {
    rl[e] = rmap[lane * 4 + e];
    cl[e] = cmap[lane * 4 + e];
  }
#pragma unroll
  for (int mi = 0; mi < 4; ++mi)
#pragma unroll
    for (int e = 0; e < 4; ++e) {
      const int rloc = wm + mi * 16 + rl[e];
      const int row = bm + rloc;
      float s = 0.f;
#pragma unroll
      for (int ni = 0; ni < 4; ++ni) {
        float p = __expf(acc[mi][ni][e] - 100.0f);
        s += p;
        P[(size_t)row * N + (bn + wn + ni * 16 + cl[e])] = f2bf(p);
      }
      s += __shfl_xor(s, 1, 64);
      s += __shfl_xor(s, 2, 64);
      s += __shfl_xor(s, 4, 64);
      s += __shfl_xor(s, 8, 64);
      if (t == 0) lrs[rloc][wave >> 2] = s;
    }
  __syncthreads();
  if (tid < 256)
    rsp[(size_t)blockIdx.x * 8192 + bm + tid] = lrs[tid][0] + lrs[tid][1];
}

// ---------------------------------------------------------------------------
// NT GEMM 128x128, BK=64 (r9 proven) — GY1 (f16) / GY2 (bf16).
// ---------------------------------------------------------------------------
template <int EPI, int F16>
__global__ __launch_bounds__(256) void gemm_nt(
    const u16* __restrict__ A, const u16* __restrict__ B, int K, int Kc, int N,
    u16* __restrict__ outp, const float* __restrict__ invl,
    const int* __restrict__ rmap, const int* __restrict__ cmap) {
  __shared__ __align__(16) u16 lA[128 * 64];
  __shared__ __align__(16) u16 lB[128 * 64];

  const int tid = threadIdx.x;
  const int wave = tid >> 6, lane = tid & 63;
  const int quad = lane >> 4, t = lane & 15;
  const int bm = blockIdx.y * 128, bn = blockIdx.x * 128;
  const int wm = (wave & 1) * 64, wn = (wave >> 1) * 64;
  const int koff = blockIdx.z * Kc;

  f32x4 acc[4][4];
#pragma unroll
  for (int i = 0; i < 4; ++i)
#pragma unroll
    for (int j = 0; j < 4; ++j) acc[i][j] = (f32x4){0.f, 0.f, 0.f, 0.f};

  const int srow = tid >> 3, schk = tid & 7;
  const u16* pA[4]; const u16* pB[4];
#pragma unroll
  for (int j = 0; j < 4; ++j) {
    const int r = j * 32 + srow;
    const int c = schk ^ swz8(r);
    pA[j] = A + (size_t)(bm + r) * K + koff + c * 8;
    pB[j] = B + (size_t)(bn + r) * K + koff + c * 8;
  }

  int aoffx[4], boffx[4];
#pragma unroll
  for (int i = 0; i < 4; ++i) {
    const int rm = wm + i * 16 + t;
    aoffx[i] = rm * 128 + (swz8(rm) << 4);
    const int rn = wn + i * 16 + t;
    boffx[i] = rn * 128 + (swz8(rn) << 4);
  }
  const int sq0 = quad << 4, sq1 = (quad << 4) | 64;

  for (int k0 = 0; k0 < Kc; k0 += 64) {
#pragma unroll
    for (int j = 0; j < 4; ++j) {
      async16(pA[j], (char*)lA + j * 4096 + wave * 1024);
      async16(pB[j], (char*)lB + j * 4096 + wave * 1024);
      pA[j] += 64; pB[j] += 64;
    }
    __syncthreads();
#pragma unroll
    for (int s = 0; s < 2; ++s) {
      const int sq = s ? sq1 : sq0;
      bf16x8 av[4], bv[4];
#pragma unroll
      for (int i = 0; i < 4; ++i) {
        av[i] = *(const bf16x8*)((const char*)lA + (aoffx[i] ^ sq));
        bv[i] = *(const bf16x8*)((const char*)lB + (boffx[i] ^ sq));
      }
#pragma unroll
      for (int mi = 0; mi < 4; ++mi)
#pragma unroll
        for (int ni = 0; ni < 4; ++ni) {
          if constexpr (F16)
            acc[mi][ni] = __builtin_amdgcn_mfma_f32_16x16x32_f16(
                __builtin_bit_cast(f16x8, av[mi]), __builtin_bit_cast(f16x8, bv[ni]),
                acc[mi][ni], 0, 0, 0);
          else
            acc[mi][ni] = __builtin_amdgcn_mfma_f32_16x16x32_bf16(av[mi], bv[ni], acc[mi][ni], 0, 0, 0);
        }
    }
    __syncthreads();
  }

  int rl[4], cl[4];
#pragma unroll
  for (int e = 0; e < 4; ++e) {
    rl[e] = rmap[lane * 4 + e];
    cl[e] = cmap[lane * 4 + e];
  }
  const size_t zoff = (size_t)blockIdx.z * ((size_t)gridDim.y * 128) * N;
#pragma unroll
  for (int mi = 0; mi < 4; ++mi)
#pragma unroll
    for (int e = 0; e < 4; ++e) {
      const int row = bm + wm + mi * 16 + rl[e];
      const float sc = (EPI == EPI_PARTH) ? invl[row] : 1.0f;
#pragma unroll
      for (int ni = 0; ni < 4; ++ni) {
        const size_t idx = (size_t)row * N + (bn + wn + ni * 16 + cl[e]);
        if (EPI == EPI_PARTH) outp[zoff + idx] = f2h(acc[mi][ni][e] * sc);
        else                  outp[idx] = f2bf(acc[mi][ni][e]);
      }
    }
}

// ---------------------------------------------------------------------------
// F2: NT GEMM 128x128, 256 thr, BK=128, 64KB LDS (2 blk/CU), FIN folded.
// r20/r21-proven bit-exact.
// ---------------------------------------------------------------------------
__global__ __launch_bounds__(256) void gemm_nt128(
    const u16* __restrict__ A, const u16* __restrict__ B, int K, int Kc, int N,
    u16* __restrict__ outp, const float* __restrict__ rsp,
    const int* __restrict__ rmap, const int* __restrict__ cmap) {
  __shared__ __align__(16) u16 lA[128 * 128];   // 32 KB
  __shared__ __align__(16) u16 lB[128 * 128];   // 32 KB
  __shared__ float linvl[128];

  const int tid = threadIdx.x;
  const int wave = tid >> 6, lane = tid & 63;
  const int quad = lane >> 4, t = lane & 15;
  const int bm = blockIdx.y * 128, bn = blockIdx.x * 128;
  const int wm = (wave & 1) * 64, wn = (wave >> 1) * 64;
  const int koff = blockIdx.z * Kc;

  if (tid < 128) {
    const int row = bm + tid;
    float s = 0.f;
#pragma unroll 8
    for (int b = 0; b < 64; ++b) s += rsp[(size_t)b * 8192 + row];
    linvl[tid] = 1.0f / s;
  }

  f32x4 acc[4][4];
#pragma unroll
  for (int i = 0; i < 4; ++i)
#pragma unroll
    for (int j = 0; j < 4; ++j) acc[i][j] = (f32x4){0.f, 0.f, 0.f, 0.f};

  const int srow = tid >> 4, schk = tid & 15;
  const u16* pA[8]; const u16* pB[8];
#pragma unroll
  for (int j = 0; j < 8; ++j) {
    const int r = j * 16 + srow;
    const int c = schk ^ swz16(r);
    pA[j] = A + (size_t)(bm + r) * K + koff + c * 8;
    pB[j] = B + (size_t)(bn + r) * K + koff + c * 8;
  }

  int aoffx[4], boffx[4];
#pragma unroll
  for (int i = 0; i < 4; ++i) {
    const int rm = wm + i * 16 + t;
    aoffx[i] = rm * 256 + (swz16(rm) << 4);
    const int rn = wn + i * 16 + t;
    boffx[i] = rn * 256 + (swz16(rn) << 4);
  }

  for (int k0 = 0; k0 < Kc; k0 += 128) {
#pragma unroll
    for (int j = 0; j < 8; ++j) {
      async16(pA[j], (char*)lA + j * 4096 + tid * 16);
      async16(pB[j], (char*)lB + j * 4096 + tid * 16);
      pA[j] += 128; pB[j] += 128;
    }
    __syncthreads();
#pragma unroll
    for (int s = 0; s < 4; ++s) {
      const int sq = (s << 6) | (quad << 4);
      bf16x8 av[4], bv[4];
#pragma unroll
      for (int i = 0; i < 4; ++i) {
        av[i] = *(const bf16x8*)((const char*)lA + (aoffx[i] ^ sq));
        bv[i] = *(const bf16x8*)((const char*)lB + (boffx[i] ^ sq));
      }
#pragma unroll
      for (int mi = 0; mi < 4; ++mi)
#pragma unroll
        for (int ni = 0; ni < 4; ++ni)
          acc[mi][ni] = __builtin_amdgcn_mfma_f32_16x16x32_bf16(av[mi], bv[ni], acc[mi][ni], 0, 0, 0);
    }
    __syncthreads();
  }

  int rl[4], cl[4];
#pragma unroll
  for (int e = 0; e < 4; ++e) {
    rl[e] = rmap[lane * 4 + e];
    cl[e] = cmap[lane * 4 + e];
  }
  const size_t zoff = (size_t)blockIdx.z * ((size_t)gridDim.y * 128) * N;
#pragma unroll
  for (int mi = 0; mi < 4; ++mi)
#pragma unroll
    for (int e = 0; e < 4; ++e) {
      const int rloc = wm + mi * 16 + rl[e];
      const int row = bm + rloc;
      const float sc = linvl[rloc];
#pragma unroll
      for (int ni = 0; ni < 4; ++ni) {
        const size_t idx = (size_t)row * N + (bn + wn + ni * 16 + cl[e]);
        outp[zoff + idx] = f2h(acc[mi][ni][e] * sc);
      }
    }
}

// ---------------------------------------------------------------------------
// F1: NT GEMM 64(m)x256(n), 256 thr (4 waves of 64x64), BK=128, LDS 80KB
// (2 blk/CU), grid (1,128,4). P read once; Y1T re-read is L3-resident (4MB).
// Staging/read scheme == gemm_nt128 (swz16, slot schk <- chunk schk^swz16(r),
// sq=(s<<6)|(quad<<4)) -> identical ascending k-chunk order -> bit-identical.
// linvl aliases lA after the k-loop (keeps LDS at exactly 80KB).
// ---------------------------------------------------------------------------
__global__ __launch_bounds__(256) void gemm_f1w64(
    const u16* __restrict__ A, const u16* __restrict__ B,
    u16* __restrict__ outp, const float* __restrict__ rsp,
    const int* __restrict__ rmap, const int* __restrict__ cmap) {
  constexpr int K = 8192, Kc = 2048, N = 256;
  __shared__ __align__(16) u16 lA[64 * 128];    // 16 KB
  __shared__ __align__(16) u16 lB[256 * 128];   // 64 KB

  const int tid = threadIdx.x;
  const int wave = tid >> 6, lane = tid & 63;
  const int quad = lane >> 4, t = lane & 15;
  const int bm = blockIdx.y * 64;               // gridDim.y = 128
  const int wn = wave * 64;
  const int koff = blockIdx.z * Kc;

  f32x4 acc[4][4];
#pragma unroll
  for (int i = 0; i < 4; ++i)
#pragma unroll
    for (int j = 0; j < 4; ++j) acc[i][j] = (f32x4){0.f, 0.f, 0.f, 0.f};

  // staging: srow = tid>>4 in [0,16), 16 chunk slots/row. For r = j*16+srow
  // (j<16): swz16(r) = (srow^j)&15 -> source chunk = (schk^srow^j)&15.
  const int srow = tid >> 4, schk = tid & 15;
  const u16* abase = A + (size_t)(bm + srow) * K + koff;
  const u16* bbase = B + (size_t)srow * K + koff;

  int aoffx[4], boffx[4];
#pragma unroll
  for (int i = 0; i < 4; ++i) {
    const int rm = i * 16 + t;                  // A rows 0..63
    aoffx[i] = rm * 256 + (swz16(rm) << 4);
    const int rn = wn + i * 16 + t;             // B rows 0..255
    boffx[i] = rn * 256 + (swz16(rn) << 4);
  }

  for (int k0 = 0; k0 < Kc; k0 += 128) {
#pragma unroll
    for (int j = 0; j < 4; ++j)
      async16(abase + k0 + (size_t)j * 16 * K + (((schk ^ srow ^ j) & 15) << 3),
              (char*)lA + j * 4096 + tid * 16);
#pragma unroll
    for (int j = 0; j < 16; ++j)
      async16(bbase + k0 + (size_t)j * 16 * K + (((schk ^ srow ^ j) & 15) << 3),
              (char*)lB + j * 4096 + tid * 16);
    __syncthreads();
#pragma unroll
    for (int s = 0; s < 4; ++s) {
      const int sq = (s << 6) | (quad << 4);
      bf16x8 av[4], bv[4];
#pragma unroll
      for (int i = 0; i < 4; ++i) {
        av[i] = *(const bf16x8*)((const char*)lA + (aoffx[i] ^ sq));
        bv[i] = *(const bf16x8*)((const char*)lB + (boffx[i] ^ sq));
      }
#pragma unroll
      for (int mi = 0; mi < 4; ++mi)
#pragma unroll
        for (int ni = 0; ni < 4; ++ni)
          acc[mi][ni] = __builtin_amdgcn_mfma_f32_16x16x32_bf16(av[mi], bv[ni], acc[mi][ni], 0, 0, 0);
    }
    __syncthreads();
  }

  // folded FIN (lA is dead now; alias it for linvl). Same b-order as FIN.
  float* linvl = (float*)lA;
  if (tid < 64) {
    const int row = bm + tid;
    float s = 0.f;
#pragma unroll 8
    for (int b = 0; b < 64; ++b) s += rsp[(size_t)b * 8192 + row];
    linvl[tid] = 1.0f / s;
  }
  __syncthreads();

  int rl[4], cl[4];
#pragma unroll
  for (int e = 0; e < 4; ++e) {
    rl[e] = rmap[lane * 4 + e];
    cl[e] = cmap[lane * 4 + e];
  }
  const size_t zoff = (size_t)blockIdx.z * 2097152;   // z * 8192 * 256
#pragma unroll
  for (int mi = 0; mi < 4; ++mi)
#pragma unroll
    for (int e = 0; e < 4; ++e) {
      const int rloc = mi * 16 + rl[e];
      const int row = bm + rloc;
      const float sc = linvl[rloc];
#pragma unroll
      for (int ni = 0; ni < 4; ++ni) {
        const size_t idx = (size_t)row * N + (wn + ni * 16 + cl[e]);
        outp[zoff + idx] = f2h(acc[mi][ni][e] * sc);
      }
    }
}

// ---------------------------------------------------------------------------
// combine1: x1 = sum4(pp) -> f32 + bf16 x1h. Vectorized (r19-proven).
// ---------------------------------------------------------------------------
__global__ __launch_bounds__(256) void combine1(
    const u16* __restrict__ pp, const float* __restrict__ invl,
    float* __restrict__ x1f, u16* __restrict__ x1h) {
  const size_t i = ((size_t)blockIdx.x * 256 + threadIdx.x) * 8;
  const bf16x8 p0 = *(const bf16x8*)(pp + i);
  const bf16x8 p1 = *(const bf16x8*)(pp + 2097152 + i);
  const bf16x8 p2 = *(const bf16x8*)(pp + 4194304 + i);
  const bf16x8 p3 = *(const bf16x8*)(pp + 6291456 + i);
  float4 o0, o1;
  bf16x8 oh;
#pragma unroll
  for (int j = 0; j < 8; ++j) {
    const float v = h2f((u16)p0[j]) + h2f((u16)p1[j]) + h2f((u16)p2[j]) + h2f((u16)p3[j]);
    if (j < 4) ((float*)&o0)[j] = v; else ((float*)&o1)[j - 4] = v;
    oh[j] = (short)f2bf(v);
  }
  *(float4*)(x1f + i) = o0;
  *(float4*)(x1f + i + 4) = o1;
  *(bf16x8*)(x1h + i) = oh;
}

// ---------------------------------------------------------------------------
// combine2: x2 = sum8(pp) -> f32. Vectorized (r19-proven).
// ---------------------------------------------------------------------------
__global__ __launch_bounds__(256) void combine2(
    const u16* __restrict__ pp, const float* __restrict__ invl,
    float* __restrict__ x2f) {
  const size_t i = ((size_t)blockIdx.x * 256 + threadIdx.x) * 8;
  float v[8] = {0.f, 0.f, 0.f, 0.f, 0.f, 0.f, 0.f, 0.f};
#pragma unroll
  for (int z = 0; z < 8; ++z) {
    const bf16x8 p = *(const bf16x8*)(pp + (size_t)z * 1048576 + i);
#pragma unroll
    for (int j = 0; j < 8; ++j) v[j] += h2f((u16)p[j]);
  }
  float4 o0, o1;
#pragma unroll
  for (int j = 0; j < 4; ++j) { ((float*)&o0)[j] = v[j]; ((float*)&o1)[j] = v[j + 4]; }
  *(float4*)(x2f + i) = o0;
  *(float4*)(x2f + i + 4) = o1;
}

// ---------------------------------------------------------------------------
extern "C" void kernel_launch(void* const* d_in, const int* in_sizes, int n_in,
                              void* d_out, int out_size, void* d_ws, size_t ws_size,
                              hipStream_t stream) {
  const float* Fs = (const float*)d_in[0];   // [8192][512]
  const float* Ft = (const float*)d_in[1];   // [8192][512]
  const float* W1 = (const float*)d_in[2];   // [256][512]
  const float* W2 = (const float*)d_in[3];   // [128][256]

  char* ws = (char*)d_ws;                    // extent <= 168134656 (proven r5-r9)
  u16*   P    = (u16*)(ws);                  // [8192][8192] bf16, 0..128MiB
  u16*   Fsf  = (u16*)(ws + 134217728);      // 8MiB f16 (dead after GY1)
  u16*   Ftf  = (u16*)(ws + 142606336);      // 8MiB f16 (dead after G2)
  u16*   pp   = (u16*)(ws + 134217728);      // 16MiB f16 partials (born F1)
  float* rsp  = (float*)(ws + 150994944);    // [64][8192] f32, ends 153092096
  u16*   Y1T  = (u16*)(ws + 153092096);      // [256][8192] 4MiB, ends 157286400
  u16*   x1h  = (u16*)(ws + 157286400);      // [8192][256] 4MiB
  u16*   Y2T  = (u16*)(ws + 161480704);      // [128][8192] 2MiB
  int*   rmap = (int*)  (ws + 163610624);
  int*   cmap = (int*)  (ws + 163611648);
  u16*   W1f  = (u16*)(ws + 163612672);      // [256][512] f16 256KiB
  u16*   W2h  = (u16*)(ws + 163874816);      // [128][256] bf16 64KiB

  float* x1f = (float*)d_out;                // [8192][256]
  float* x2f = (float*)d_out + 2097152;      // [8192][128]

  dim3 blk(256);
  conv_probe<<<4177, blk, 0, stream>>>(Fs, Ft, W1, W2, Fsf, Ftf, W1f, W2h, rmap, cmap);
  gemm_pexp_f16_256<<<dim3(64, 32), dim3(512), 0, stream>>>(
      Fsf, Ftf, 512, 8192, P, rsp, rmap, cmap);
  gemm_nt<EPI_STOREB, 1><<<dim3(64, 2), blk, 0, stream>>>(
      W1f, Fsf, 512, 512, 8192, Y1T, nullptr, rmap, cmap);
  // F1: 64x256 tile, BK=128, split-K=4, 512 blocks = 2 blk/CU, FIN folded
  gemm_f1w64<<<dim3(1, 128, 4), blk, 0, stream>>>(
      P, Y1T, pp, rsp, rmap, cmap);
  combine1<<<1024, blk, 0, stream>>>(pp, nullptr, x1f, x1h);
  gemm_nt<EPI_STOREB, 0><<<dim3(64, 1), blk, 0, stream>>>(
      W2h, x1h, 256, 256, 8192, Y2T, nullptr, rmap, cmap);
  // F2: BK=128, 128x128, split-K=8, FIN folded
  gemm_nt128<<<dim3(1, 64, 8), blk, 0, stream>>>(
      P, Y2T, 8192, 1024, 128, pp, rsp, rmap, cmap);
  combine2<<<512, blk, 0, stream>>>(pp, nullptr, x2f);
}

// Round 12
// 271.085 us; speedup vs baseline: 1.0170x; 1.0170x over previous
//
#include <hip/hip_runtime.h>
#include <stdint.h>

// SimpleGCN, f32 in / f32 out. Round 23 = r21 VERBATIM (273.3us, session
// best) — r22's F1 64x256 retile regressed (+2.4us: halved M-tile doubled
// B-staging traffic, cancelling the 2blk/CU TLP gain). Final configuration:
//   - FIN folded into F1/F2 prologues (r21-proven, -3.5us)
//   - F1: gemm_ntw128 128x256, BK=128, split-K=4 (P read once)
//   - F2: gemm_nt128 128x128, BK=128, split-K=8 (2 blk/CU)
//   - G2: 256x128 f16, BK=64 (proven ceiling of 2-barrier structure)
// 8 dispatches. All FP orders preserved -> absmax 0.05078125.
//   conv: Fs,Ft,W1 -> f16; W2 -> bf16 (+ MFMA layout probe)
//   G2 : S = Fsf@Ftf^T (f16); P~=exp(S-100)->bf16 [8192][8192] + rowsum partials
//   GY1: Y1T = W1f@Fsf^T (f16) -> bf16 [256][8192]
//   F1 : pp[z] = invl(.)(P~ @ Y1), BK=128 128x256, split-K=4, FIN folded
//   C1 : x1 = sum4(pp) -> f32 d_out + bf16 x1h
//   GY2: Y2T = W2h@x1h^T (bf16) -> bf16 [128][8192]
//   F2 : pp[z] = invl(.)(P~ @ Y2), BK=128 128x128, split-K=8, FIN folded
//   C2 : x2 = sum8(pp) -> f32 d_out
// NT GEMMs; BK=64 kernels: 128B LDS rows + swz8; BK=128: 256B rows + swz16.
// Epilogue coords from runtime probe (rmap/cmap).

typedef unsigned short u16;
typedef short bf16x8 __attribute__((ext_vector_type(8)));
typedef _Float16 f16x8 __attribute__((ext_vector_type(8)));
typedef float f32x4 __attribute__((ext_vector_type(4)));

#define EPI_STOREB 0
#define EPI_PARTH  1

__device__ __forceinline__ u16 f2bf(float f) {
  unsigned u = __float_as_uint(f);
  u += 0x7fffu + ((u >> 16) & 1u);
  return (u16)(u >> 16);
}
__device__ __forceinline__ u16 f2h(float f) {
  union { _Float16 h; u16 u; } cv; cv.h = (_Float16)f; return cv.u;
}
__device__ __forceinline__ float h2f(u16 u) {
  union { u16 u; _Float16 h; } cv; cv.u = u; return (float)cv.h;
}
__device__ __forceinline__ int swz8(int r) { return (r ^ (r >> 3)) & 7; }
__device__ __forceinline__ int swz16(int r) { return (r ^ (r >> 4)) & 15; }

__device__ __forceinline__ void async16(const void* g, void* lds) {
  __builtin_amdgcn_global_load_lds(
      (const __attribute__((address_space(1))) unsigned int*)g,
      (__attribute__((address_space(3))) unsigned int*)lds, 16, 0, 0);
}

// ---------------------------------------------------------------------------
// conv + layout probe (r14-proven).
// ---------------------------------------------------------------------------
__global__ __launch_bounds__(256) void conv_probe(
    const float* __restrict__ Fs, const float* __restrict__ Ft,
    const float* __restrict__ W1, const float* __restrict__ W2,
    u16* __restrict__ Fsf, u16* __restrict__ Ftf,
    u16* __restrict__ W1f, u16* __restrict__ W2h,
    int* __restrict__ rmap, int* __restrict__ cmap) {
  const int bx = blockIdx.x, tid = threadIdx.x;
  if (bx < 4176) {
    const float* src; u16* dst; size_t i; bool tobf = false;
    if (bx < 2048)      { src = Fs; dst = Fsf; i = ((size_t)bx * 256 + tid) * 8; }
    else if (bx < 4096) { src = Ft; dst = Ftf; i = ((size_t)(bx - 2048) * 256 + tid) * 8; }
    else if (bx < 4160) { src = W1; dst = W1f; i = ((size_t)(bx - 4096) * 256 + tid) * 8; }
    else                { src = W2; dst = W2h; i = ((size_t)(bx - 4160) * 256 + tid) * 8; tobf = true; }
    const float4 a = *(const float4*)(src + i);
    const float4 b = *(const float4*)(src + i + 4);
    bf16x8 o;
    if (tobf) {
      o[0] = (short)f2bf(a.x); o[1] = (short)f2bf(a.y); o[2] = (short)f2bf(a.z); o[3] = (short)f2bf(a.w);
      o[4] = (short)f2bf(b.x); o[5] = (short)f2bf(b.y); o[6] = (short)f2bf(b.z); o[7] = (short)f2bf(b.w);
    } else {
      o[0] = (short)f2h(a.x); o[1] = (short)f2h(a.y); o[2] = (short)f2h(a.z); o[3] = (short)f2h(a.w);
      o[4] = (short)f2h(b.x); o[5] = (short)f2h(b.y); o[6] = (short)f2h(b.z); o[7] = (short)f2h(b.w);
    }
    *(bf16x8*)(dst + i) = o;
    return;
  }
  if (tid >= 64) return;
  const int lane = tid & 63;
  const int t = lane & 15, quad = lane >> 4;
  bf16x8 avt, av1;
  const u16 bt = f2bf((float)t), b1 = 0x3f80;
#pragma unroll
  for (int j = 0; j < 8; ++j) { ((u16*)&avt)[j] = bt; ((u16*)&av1)[j] = b1; }
  f32x4 z = {0.f, 0.f, 0.f, 0.f};
  f32x4 r1 = __builtin_amdgcn_mfma_f32_16x16x32_bf16(avt, av1, z, 0, 0, 0);
  f32x4 r2 = __builtin_amdgcn_mfma_f32_16x16x32_bf16(av1, avt, z, 0, 0, 0);
#pragma unroll
  for (int e = 0; e < 4; ++e) {
    int r = (int)(r1[e] * 0.03125f + 0.5f);
    int c = (int)(r2[e] * 0.03125f + 0.5f);
    if (r < 0 || r > 15) r = quad * 4 + e;
    if (c < 0 || c > 15) c = t;
    rmap[lane * 4 + e] = r;
    cmap[lane * 4 + e] = c;
  }
}

// ---------------------------------------------------------------------------
// G2: f16 NT GEMM, 256x128 tile, 512 threads, BK=64 (r9/r11 proven, ~92us).
// ---------------------------------------------------------------------------
__global__ __launch_bounds__(512) void gemm_pexp_f16_256(
    const u16* __restrict__ A, const u16* __restrict__ B, int K, int N,
    u16* __restrict__ P, float* __restrict__ rsp,
    const int* __restrict__ rmap, const int* __restrict__ cmap) {
  __shared__ __align__(16) u16 lA[256 * 64];
  __shared__ __align__(16) u16 lB[128 * 64];
  __shared__ float lrs[256][2];

  const int tid = threadIdx.x;
  const int wave = tid >> 6, lane = tid & 63;
  const int quad = lane >> 4, t = lane & 15;
  const int bm = blockIdx.y * 256, bn = blockIdx.x * 128;
  const int wm = (wave & 3) * 64, wn = (wave >> 2) * 64;

  f32x4 acc[4][4];
#pragma unroll
  for (int i = 0; i < 4; ++i)
#pragma unroll
    for (int j = 0; j < 4; ++j) acc[i][j] = (f32x4){0.f, 0.f, 0.f, 0.f};

  const int srow = tid >> 3, schk = tid & 7;
  const u16* pA[4]; const u16* pB[2];
#pragma unroll
  for (int j = 0; j < 4; ++j) {
    const int r = j * 64 + srow;
    pA[j] = A + (size_t)(bm + r) * K + (schk ^ swz8(r)) * 8;
  }
#pragma unroll
  for (int j = 0; j < 2; ++j) {
    const int r = j * 64 + srow;
    pB[j] = B + (size_t)(bn + r) * K + (schk ^ swz8(r)) * 8;
  }

  int aoffx[4], boffx[4];
#pragma unroll
  for (int i = 0; i < 4; ++i) {
    const int rm = wm + i * 16 + t;
    aoffx[i] = rm * 128 + (swz8(rm) << 4);
    const int rn = wn + i * 16 + t;
    boffx[i] = rn * 128 + (swz8(rn) << 4);
  }
  const int sq0 = quad << 4, sq1 = (quad << 4) | 64;

  for (int k0 = 0; k0 < K; k0 += 64) {
#pragma unroll
    for (int j = 0; j < 4; ++j) {
      async16(pA[j], (char*)lA + j * 8192 + wave * 1024);
      pA[j] += 64;
    }
#pragma unroll
    for (int j = 0; j < 2; ++j) {
      async16(pB[j], (char*)lB + j * 8192 + wave * 1024);
      pB[j] += 64;
    }
    __syncthreads();
#pragma unroll
    for (int s = 0; s < 2; ++s) {
      const int sq = s ? sq1 : sq0;
      f16x8 av[4], bv[4];
#pragma unroll
      for (int i = 0; i < 4; ++i) {
        av[i] = *(const f16x8*)((const char*)lA + (aoffx[i] ^ sq));
        bv[i] = *(const f16x8*)((const char*)lB + (boffx[i] ^ sq));
      }
#pragma unroll
      for (int mi = 0; mi < 4; ++mi)
#pragma unroll
        for (int ni = 0; ni < 4; ++ni)
          acc[mi][ni] = __builtin_amdgcn_mfma_f32_16x16x32_f16(av[mi], bv[ni], acc[mi][ni], 0, 0, 0);
    }
    __syncthreads();
  }

  int rl[4], cl[4];
#pragma unroll
  for (int e = 0; e < 4; ++e) {
    rl[e] = rmap[lane * 4 + e];
    cl[e] = cmap[lane * 4 + e];
  }
#pragma unroll
  for (int mi = 0; mi < 4; ++mi)
#pragma unroll
    for (int e = 0; e < 4; ++e) {
      const int rloc = wm + mi * 16 + rl[e];
      const int row = bm + rloc;
      float s = 0.f;
#pragma unroll
      for (int ni = 0; ni < 4; ++ni) {
        float p = __expf(acc[mi][ni][e] - 100.0f);
        s += p;
        P[(size_t)row * N + (bn + wn + ni * 16 + cl[e])] = f2bf(p);
      }
      s += __shfl_xor(s, 1, 64);
      s += __shfl_xor(s, 2, 64);
      s += __shfl_xor(s, 4, 64);
      s += __shfl_xor(s, 8, 64);
      if (t == 0) lrs[rloc][wave >> 2] = s;
    }
  __syncthreads();
  if (tid < 256)
    rsp[(size_t)blockIdx.x * 8192 + bm + tid] = lrs[tid][0] + lrs[tid][1];
}

// ---------------------------------------------------------------------------
// NT GEMM 128x128, BK=64 (r9 proven) — GY1 (f16) / GY2 (bf16).
// ---------------------------------------------------------------------------
template <int EPI, int F16>
__global__ __launch_bounds__(256) void gemm_nt(
    const u16* __restrict__ A, const u16* __restrict__ B, int K, int Kc, int N,
    u16* __restrict__ outp, const float* __restrict__ invl,
    const int* __restrict__ rmap, const int* __restrict__ cmap) {
  __shared__ __align__(16) u16 lA[128 * 64];
  __shared__ __align__(16) u16 lB[128 * 64];

  const int tid = threadIdx.x;
  const int wave = tid >> 6, lane = tid & 63;
  const int quad = lane >> 4, t = lane & 15;
  const int bm = blockIdx.y * 128, bn = blockIdx.x * 128;
  const int wm = (wave & 1) * 64, wn = (wave >> 1) * 64;
  const int koff = blockIdx.z * Kc;

  f32x4 acc[4][4];
#pragma unroll
  for (int i = 0; i < 4; ++i)
#pragma unroll
    for (int j = 0; j < 4; ++j) acc[i][j] = (f32x4){0.f, 0.f, 0.f, 0.f};

  const int srow = tid >> 3, schk = tid & 7;
  const u16* pA[4]; const u16* pB[4];
#pragma unroll
  for (int j = 0; j < 4; ++j) {
    const int r = j * 32 + srow;
    const int c = schk ^ swz8(r);
    pA[j] = A + (size_t)(bm + r) * K + koff + c * 8;
    pB[j] = B + (size_t)(bn + r) * K + koff + c * 8;
  }

  int aoffx[4], boffx[4];
#pragma unroll
  for (int i = 0; i < 4; ++i) {
    const int rm = wm + i * 16 + t;
    aoffx[i] = rm * 128 + (swz8(rm) << 4);
    const int rn = wn + i * 16 + t;
    boffx[i] = rn * 128 + (swz8(rn) << 4);
  }
  const int sq0 = quad << 4, sq1 = (quad << 4) | 64;

  for (int k0 = 0; k0 < Kc; k0 += 64) {
#pragma unroll
    for (int j = 0; j < 4; ++j) {
      async16(pA[j], (char*)lA + j * 4096 + wave * 1024);
      async16(pB[j], (char*)lB + j * 4096 + wave * 1024);
      pA[j] += 64; pB[j] += 64;
    }
    __syncthreads();
#pragma unroll
    for (int s = 0; s < 2; ++s) {
      const int sq = s ? sq1 : sq0;
      bf16x8 av[4], bv[4];
#pragma unroll
      for (int i = 0; i < 4; ++i) {
        av[i] = *(const bf16x8*)((const char*)lA + (aoffx[i] ^ sq));
        bv[i] = *(const bf16x8*)((const char*)lB + (boffx[i] ^ sq));
      }
#pragma unroll
      for (int mi = 0; mi < 4; ++mi)
#pragma unroll
        for (int ni = 0; ni < 4; ++ni) {
          if constexpr (F16)
            acc[mi][ni] = __builtin_amdgcn_mfma_f32_16x16x32_f16(
                __builtin_bit_cast(f16x8, av[mi]), __builtin_bit_cast(f16x8, bv[ni]),
                acc[mi][ni], 0, 0, 0);
          else
            acc[mi][ni] = __builtin_amdgcn_mfma_f32_16x16x32_bf16(av[mi], bv[ni], acc[mi][ni], 0, 0, 0);
        }
    }
    __syncthreads();
  }

  int rl[4], cl[4];
#pragma unroll
  for (int e = 0; e < 4; ++e) {
    rl[e] = rmap[lane * 4 + e];
    cl[e] = cmap[lane * 4 + e];
  }
  const size_t zoff = (size_t)blockIdx.z * ((size_t)gridDim.y * 128) * N;
#pragma unroll
  for (int mi = 0; mi < 4; ++mi)
#pragma unroll
    for (int e = 0; e < 4; ++e) {
      const int row = bm + wm + mi * 16 + rl[e];
      const float sc = (EPI == EPI_PARTH) ? invl[row] : 1.0f;
#pragma unroll
      for (int ni = 0; ni < 4; ++ni) {
        const size_t idx = (size_t)row * N + (bn + wn + ni * 16 + cl[e]);
        if (EPI == EPI_PARTH) outp[zoff + idx] = f2h(acc[mi][ni][e] * sc);
        else                  outp[idx] = f2bf(acc[mi][ni][e]);
      }
    }
}

// ---------------------------------------------------------------------------
// F2: NT GEMM 128x128, 256 thr, BK=128, 64KB LDS (2 blk/CU), FIN folded.
// r20/r21-proven bit-exact.
// ---------------------------------------------------------------------------
__global__ __launch_bounds__(256) void gemm_nt128(
    const u16* __restrict__ A, const u16* __restrict__ B, int K, int Kc, int N,
    u16* __restrict__ outp, const float* __restrict__ rsp,
    const int* __restrict__ rmap, const int* __restrict__ cmap) {
  __shared__ __align__(16) u16 lA[128 * 128];   // 32 KB
  __shared__ __align__(16) u16 lB[128 * 128];   // 32 KB
  __shared__ float linvl[128];

  const int tid = threadIdx.x;
  const int wave = tid >> 6, lane = tid & 63;
  const int quad = lane >> 4, t = lane & 15;
  const int bm = blockIdx.y * 128, bn = blockIdx.x * 128;
  const int wm = (wave & 1) * 64, wn = (wave >> 1) * 64;
  const int koff = blockIdx.z * Kc;

  if (tid < 128) {
    const int row = bm + tid;
    float s = 0.f;
#pragma unroll 8
    for (int b = 0; b < 64; ++b) s += rsp[(size_t)b * 8192 + row];
    linvl[tid] = 1.0f / s;
  }

  f32x4 acc[4][4];
#pragma unroll
  for (int i = 0; i < 4; ++i)
#pragma unroll
    for (int j = 0; j < 4; ++j) acc[i][j] = (f32x4){0.f, 0.f, 0.f, 0.f};

  const int srow = tid >> 4, schk = tid & 15;
  const u16* pA[8]; const u16* pB[8];
#pragma unroll
  for (int j = 0; j < 8; ++j) {
    const int r = j * 16 + srow;
    const int c = schk ^ swz16(r);
    pA[j] = A + (size_t)(bm + r) * K + koff + c * 8;
    pB[j] = B + (size_t)(bn + r) * K + koff + c * 8;
  }

  int aoffx[4], boffx[4];
#pragma unroll
  for (int i = 0; i < 4; ++i) {
    const int rm = wm + i * 16 + t;
    aoffx[i] = rm * 256 + (swz16(rm) << 4);
    const int rn = wn + i * 16 + t;
    boffx[i] = rn * 256 + (swz16(rn) << 4);
  }

  for (int k0 = 0; k0 < Kc; k0 += 128) {
#pragma unroll
    for (int j = 0; j < 8; ++j) {
      async16(pA[j], (char*)lA + j * 4096 + tid * 16);
      async16(pB[j], (char*)lB + j * 4096 + tid * 16);
      pA[j] += 128; pB[j] += 128;
    }
    __syncthreads();
#pragma unroll
    for (int s = 0; s < 4; ++s) {
      const int sq = (s << 6) | (quad << 4);
      bf16x8 av[4], bv[4];
#pragma unroll
      for (int i = 0; i < 4; ++i) {
        av[i] = *(const bf16x8*)((const char*)lA + (aoffx[i] ^ sq));
        bv[i] = *(const bf16x8*)((const char*)lB + (boffx[i] ^ sq));
      }
#pragma unroll
      for (int mi = 0; mi < 4; ++mi)
#pragma unroll
        for (int ni = 0; ni < 4; ++ni)
          acc[mi][ni] = __builtin_amdgcn_mfma_f32_16x16x32_bf16(av[mi], bv[ni], acc[mi][ni], 0, 0, 0);
    }
    __syncthreads();
  }

  int rl[4], cl[4];
#pragma unroll
  for (int e = 0; e < 4; ++e) {
    rl[e] = rmap[lane * 4 + e];
    cl[e] = cmap[lane * 4 + e];
  }
  const size_t zoff = (size_t)blockIdx.z * ((size_t)gridDim.y * 128) * N;
#pragma unroll
  for (int mi = 0; mi < 4; ++mi)
#pragma unroll
    for (int e = 0; e < 4; ++e) {
      const int rloc = wm + mi * 16 + rl[e];
      const int row = bm + rloc;
      const float sc = linvl[rloc];
#pragma unroll
      for (int ni = 0; ni < 4; ++ni) {
        const size_t idx = (size_t)row * N + (bn + wn + ni * 16 + cl[e]);
        outp[zoff + idx] = f2h(acc[mi][ni][e] * sc);
      }
    }
}

// ---------------------------------------------------------------------------
// F1: NT GEMM 128(m)x256(n), 512 thr, BK=128, 96KB LDS, FIN folded.
// P read once. r20/r21-proven bit-exact.
// ---------------------------------------------------------------------------
__global__ __launch_bounds__(512) void gemm_ntw128(
    const u16* __restrict__ A, const u16* __restrict__ B, int K, int Kc, int N,
    u16* __restrict__ outp, const float* __restrict__ rsp,
    const int* __restrict__ rmap, const int* __restrict__ cmap) {
  __shared__ __align__(16) u16 lA[128 * 128];   // 32 KB
  __shared__ __align__(16) u16 lB[256 * 128];   // 64 KB
  __shared__ float linvl[128];

  const int tid = threadIdx.x;
  const int wave = tid >> 6, lane = tid & 63;
  const int quad = lane >> 4, t = lane & 15;
  const int bm = blockIdx.y * 128, bn = blockIdx.x * 256;
  const int wm = (wave >> 2) * 64, wn = (wave & 3) * 64;
  const int koff = blockIdx.z * Kc;

  if (tid < 128) {
    const int row = bm + tid;
    float s = 0.f;
#pragma unroll 8
    for (int b = 0; b < 64; ++b) s += rsp[(size_t)b * 8192 + row];
    linvl[tid] = 1.0f / s;
  }

  f32x4 acc[4][4];
#pragma unroll
  for (int i = 0; i < 4; ++i)
#pragma unroll
    for (int j = 0; j < 4; ++j) acc[i][j] = (f32x4){0.f, 0.f, 0.f, 0.f};

  const int srow = tid >> 4, schk = tid & 15;
  const u16* pA[4]; const u16* pB[8];
#pragma unroll
  for (int j = 0; j < 4; ++j) {
    const int r = j * 32 + srow;
    pA[j] = A + (size_t)(bm + r) * K + koff + (schk ^ swz16(r)) * 8;
  }
#pragma unroll
  for (int j = 0; j < 8; ++j) {
    const int r = j * 32 + srow;
    pB[j] = B + (size_t)(bn + r) * K + koff + (schk ^ swz16(r)) * 8;
  }

  int aoffx[4], boffx[4];
#pragma unroll
  for (int i = 0; i < 4; ++i) {
    const int rm = wm + i * 16 + t;
    aoffx[i] = rm * 256 + (swz16(rm) << 4);
    const int rn = wn + i * 16 + t;
    boffx[i] = rn * 256 + (swz16(rn) << 4);
  }

  for (int k0 = 0; k0 < Kc; k0 += 128) {
#pragma unroll
    for (int j = 0; j < 4; ++j) {
      async16(pA[j], (char*)lA + j * 8192 + tid * 16);
      pA[j] += 128;
    }
#pragma unroll
    for (int j = 0; j < 8; ++j) {
      async16(pB[j], (char*)lB + j * 8192 + tid * 16);
      pB[j] += 128;
    }
    __syncthreads();
#pragma unroll
    for (int s = 0; s < 4; ++s) {
      const int sq = (s << 6) | (quad << 4);
      bf16x8 av[4], bv[4];
#pragma unroll
      for (int i = 0; i < 4; ++i) {
        av[i] = *(const bf16x8*)((const char*)lA + (aoffx[i] ^ sq));
        bv[i] = *(const bf16x8*)((const char*)lB + (boffx[i] ^ sq));
      }
#pragma unroll
      for (int mi = 0; mi < 4; ++mi)
#pragma unroll
        for (int ni = 0; ni < 4; ++ni)
          acc[mi][ni] = __builtin_amdgcn_mfma_f32_16x16x32_bf16(av[mi], bv[ni], acc[mi][ni], 0, 0, 0);
    }
    __syncthreads();
  }

  int rl[4], cl[4];
#pragma unroll
  for (int e = 0; e < 4; ++e) {
    rl[e] = rmap[lane * 4 + e];
    cl[e] = cmap[lane * 4 + e];
  }
  const size_t zoff = (size_t)blockIdx.z * ((size_t)gridDim.y * 128) * N;
#pragma unroll
  for (int mi = 0; mi < 4; ++mi)
#pragma unroll
    for (int e = 0; e < 4; ++e) {
      const int rloc = wm + mi * 16 + rl[e];
      const int row = bm + rloc;
      const float sc = linvl[rloc];
#pragma unroll
      for (int ni = 0; ni < 4; ++ni) {
        const size_t idx = (size_t)row * N + (bn + wn + ni * 16 + cl[e]);
        outp[zoff + idx] = f2h(acc[mi][ni][e] * sc);
      }
    }
}

// ---------------------------------------------------------------------------
// combine1: x1 = sum4(pp) -> f32 + bf16 x1h. Vectorized (r19-proven).
// ---------------------------------------------------------------------------
__global__ __launch_bounds__(256) void combine1(
    const u16* __restrict__ pp, const float* __restrict__ invl,
    float* __restrict__ x1f, u16* __restrict__ x1h) {
  const size_t i = ((size_t)blockIdx.x * 256 + threadIdx.x) * 8;
  const bf16x8 p0 = *(const bf16x8*)(pp + i);
  const bf16x8 p1 = *(const bf16x8*)(pp + 2097152 + i);
  const bf16x8 p2 = *(const bf16x8*)(pp + 4194304 + i);
  const bf16x8 p3 = *(const bf16x8*)(pp + 6291456 + i);
  float4 o0, o1;
  bf16x8 oh;
#pragma unroll
  for (int j = 0; j < 8; ++j) {
    const float v = h2f((u16)p0[j]) + h2f((u16)p1[j]) + h2f((u16)p2[j]) + h2f((u16)p3[j]);
    if (j < 4) ((float*)&o0)[j] = v; else ((float*)&o1)[j - 4] = v;
    oh[j] = (short)f2bf(v);
  }
  *(float4*)(x1f + i) = o0;
  *(float4*)(x1f + i + 4) = o1;
  *(bf16x8*)(x1h + i) = oh;
}

// ---------------------------------------------------------------------------
// combine2: x2 = sum8(pp) -> f32. Vectorized (r19-proven).
// ---------------------------------------------------------------------------
__global__ __launch_bounds__(256) void combine2(
    const u16* __restrict__ pp, const float* __restrict__ invl,
    float* __restrict__ x2f) {
  const size_t i = ((size_t)blockIdx.x * 256 + threadIdx.x) * 8;
  float v[8] = {0.f, 0.f, 0.f, 0.f, 0.f, 0.f, 0.f, 0.f};
#pragma unroll
  for (int z = 0; z < 8; ++z) {
    const bf16x8 p = *(const bf16x8*)(pp + (size_t)z * 1048576 + i);
#pragma unroll
    for (int j = 0; j < 8; ++j) v[j] += h2f((u16)p[j]);
  }
  float4 o0, o1;
#pragma unroll
  for (int j = 0; j < 4; ++j) { ((float*)&o0)[j] = v[j]; ((float*)&o1)[j] = v[j + 4]; }
  *(float4*)(x2f + i) = o0;
  *(float4*)(x2f + i + 4) = o1;
}

// ---------------------------------------------------------------------------
extern "C" void kernel_launch(void* const* d_in, const int* in_sizes, int n_in,
                              void* d_out, int out_size, void* d_ws, size_t ws_size,
                              hipStream_t stream) {
  const float* Fs = (const float*)d_in[0];   // [8192][512]
  const float* Ft = (const float*)d_in[1];   // [8192][512]
  const float* W1 = (const float*)d_in[2];   // [256][512]
  const float* W2 = (const float*)d_in[3];   // [128][256]

  char* ws = (char*)d_ws;                    // extent <= 168134656 (proven r5-r9)
  u16*   P    = (u16*)(ws);                  // [8192][8192] bf16, 0..128MiB
  u16*   Fsf  = (u16*)(ws + 134217728);      // 8MiB f16 (dead after GY1)
  u16*   Ftf  = (u16*)(ws + 142606336);      // 8MiB f16 (dead after G2)
  u16*   pp   = (u16*)(ws + 134217728);      // 16MiB f16 partials (born F1)
  float* rsp  = (float*)(ws + 150994944);    // [64][8192] f32, ends 153092096
  u16*   Y1T  = (u16*)(ws + 153092096);      // [256][8192] 4MiB, ends 157286400
  u16*   x1h  = (u16*)(ws + 157286400);      // [8192][256] 4MiB
  u16*   Y2T  = (u16*)(ws + 161480704);      // [128][8192] 2MiB
  int*   rmap = (int*)  (ws + 163610624);
  int*   cmap = (int*)  (ws + 163611648);
  u16*   W1f  = (u16*)(ws + 163612672);      // [256][512] f16 256KiB
  u16*   W2h  = (u16*)(ws + 163874816);      // [128][256] bf16 64KiB

  float* x1f = (float*)d_out;                // [8192][256]
  float* x2f = (float*)d_out + 2097152;      // [8192][128]

  dim3 blk(256);
  conv_probe<<<4177, blk, 0, stream>>>(Fs, Ft, W1, W2, Fsf, Ftf, W1f, W2h, rmap, cmap);
  gemm_pexp_f16_256<<<dim3(64, 32), dim3(512), 0, stream>>>(
      Fsf, Ftf, 512, 8192, P, rsp, rmap, cmap);
  gemm_nt<EPI_STOREB, 1><<<dim3(64, 2), blk, 0, stream>>>(
      W1f, Fsf, 512, 512, 8192, Y1T, nullptr, rmap, cmap);
  // F1: BK=128, 128x256, split-K=4, FIN folded (reads rsp)
  gemm_ntw128<<<dim3(1, 64, 4), dim3(512), 0, stream>>>(
      P, Y1T, 8192, 2048, 256, pp, rsp, rmap, cmap);
  combine1<<<1024, blk, 0, stream>>>(pp, nullptr, x1f, x1h);
  gemm_nt<EPI_STOREB, 0><<<dim3(64, 1), blk, 0, stream>>>(
      W2h, x1h, 256, 256, 8192, Y2T, nullptr, rmap, cmap);
  // F2: BK=128, 128x128, split-K=8, FIN folded
  gemm_nt128<<<dim3(1, 64, 8), blk, 0, stream>>>(
      P, Y2T, 8192, 1024, 128, pp, rsp, rmap, cmap);
  combine2<<<512, blk, 0, stream>>>(pp, nullptr, x2f);
}